// Round 6
// baseline (12805.762 us; speedup 1.0000x reference)
//
#include <hip/hip_runtime.h>

typedef __attribute__((ext_vector_type(8))) short bf16x8;
typedef __attribute__((ext_vector_type(4))) float f32x4;
typedef __attribute__((ext_vector_type(2))) float f32x2;

constexpr int   HD      = 128;
constexpr float T_NEAR  = 0.2f;
constexpr float T_FAR   = 2.0f;
constexpr float ALPHA_C = 100.0f;
constexpr int   MARCH_N = 32;
constexpr float HIT_EPS = 0.005f;
constexpr int   TP_N    = 32;
constexpr float STEP    = 0.0634765625f;  // (2.0 + 0.5*(2/32))/32, exact

// ---------- bf16 helpers ----------
__device__ __forceinline__ unsigned short f2bf(float x) {
  unsigned u = __float_as_uint(x);
  unsigned r = 0x7fffu + ((u >> 16) & 1u);
  return (unsigned short)((u + r) >> 16);
}
__device__ __forceinline__ unsigned pack2(float lo, float hi) {
  return (unsigned)f2bf(lo) | ((unsigned)f2bf(hi) << 16);
}
__device__ __forceinline__ float blo(unsigned u) { return __uint_as_float(u << 16); }
__device__ __forceinline__ float bhi(unsigned u) { return __uint_as_float(u & 0xffff0000u); }

union U8 { bf16x8 v; uint4 u4; unsigned short us[8]; };

__device__ __forceinline__ f32x2 pk_fma(f32x2 a, f32x2 b, f32x2 c) {
  f32x2 d;
  asm("v_pk_fma_f32 %0, %1, %2, %3" : "=v"(d) : "v"(a), "v"(b), "v"(c));
  return d;
}

// {h.x,h.y} -> packed bf16 pair (round-half-up) with relu in bf16-bit domain.
__device__ __forceinline__ unsigned pack_relu_pair(f32x2 h) {
  unsigned u0 = __float_as_uint(h.x) + 0x8000u;
  unsigned u1 = __float_as_uint(h.y) + 0x8000u;
  unsigned w, r;
  asm("v_perm_b32 %0, %1, %2, %3" : "=v"(w) : "v"(u1), "v"(u0), "s"(0x07060302u));
  asm("v_pk_max_i16 %0, %1, %2" : "=v"(r) : "v"(w), "v"(0u));
  return r;
}

// ---------- setup kernel: pack W2^T into per-lane MFMA A-fragments ----------
__global__ void pack_w2(const float* __restrict__ W2,
                        unsigned short* __restrict__ hi,
                        unsigned short* __restrict__ lo) {
  int idx = blockIdx.x * 256 + threadIdx.x;     // 0..16383
  int j = idx & 7, l = (idx >> 3) & 63, t = (idx >> 9) & 7, s = idx >> 12;
  int m = 16 * t + (l & 15);
  int k = 32 * s + (l >> 4) * 8 + j;
  float w = W2[k * HD + m];
  unsigned short h = f2bf(w);
  float hf = __uint_as_float(((unsigned)h) << 16);
  hi[idx] = h;
  lo[idx] = f2bf(w - hf);
}

// ---------- fast bf16 MFMA SDF eval (slim registers: ap fp32, cp bf16) ----------
__device__ __forceinline__ float sdf_fast(float t,
    const bf16x8 (&w2f)[4][8], const f32x2 (&ap)[16], const unsigned (&cpk)[16],
    const f32x4* __restrict__ sB2q, const float4* __restrict__ sW3q, float b3v)
{
  f32x2 t2; t2.x = t; t2.y = t;

  f32x4 acc[8];
  #pragma unroll
  for (int u = 0; u < 8; ++u) acc[u] = sB2q[u];   // C-init = b2 (LDS broadcast)

  #pragma unroll
  for (int s = 0; s < 4; ++s) {
    U8 B;
    {
      unsigned uc0 = cpk[4*s+0], uc1 = cpk[4*s+1], uc2 = cpk[4*s+2], uc3 = cpk[4*s+3];
      f32x2 c0; c0.x = blo(uc0); c0.y = bhi(uc0);
      f32x2 c1; c1.x = blo(uc1); c1.y = bhi(uc1);
      f32x2 c2; c2.x = blo(uc2); c2.y = bhi(uc2);
      f32x2 c3; c3.x = blo(uc3); c3.y = bhi(uc3);
      B.u4.x = pack_relu_pair(pk_fma(c0, t2, ap[4*s+0]));
      B.u4.y = pack_relu_pair(pk_fma(c1, t2, ap[4*s+1]));
      B.u4.z = pack_relu_pair(pk_fma(c2, t2, ap[4*s+2]));
      B.u4.w = pack_relu_pair(pk_fma(c3, t2, ap[4*s+3]));
    }
    #pragma unroll
    for (int u = 0; u < 8; ++u)
      acc[u] = __builtin_amdgcn_mfma_f32_16x16x32_bf16(w2f[s][u], B.v, acc[u], 0, 0, 0);
  }

  f32x2 z; z.x = 0.f; z.y = 0.f;
  f32x2 e0 = z, e1 = z, e2 = z, e3 = z;
  #pragma unroll
  for (int u = 0; u < 8; ++u) {
    float4 wv = sW3q[u];
    f32x2 wa; wa.x = wv.x; wa.y = wv.y;
    f32x2 wb; wb.x = wv.z; wb.y = wv.w;
    f32x4 y = acc[u];
    f32x2 lo; lo.x = fmaxf(y.x, 0.f); lo.y = fmaxf(y.y, 0.f);
    f32x2 hi; hi.x = fmaxf(y.z, 0.f); hi.y = fmaxf(y.w, 0.f);
    if (u & 1) { e2 = pk_fma(lo, wa, e2); e3 = pk_fma(hi, wb, e3); }
    else       { e0 = pk_fma(lo, wa, e0); e1 = pk_fma(hi, wb, e1); }
  }
  float d = (e0.x + e0.y) + (e1.x + e1.y) + ((e2.x + e2.y) + (e3.x + e3.y));
  d += __shfl_xor(d, 16);
  d += __shfl_xor(d, 32);
  return d + b3v;
}

// ---------- hi/lo-split precise eval (x100 tput channel) ----------
// Recomputes fp32 a,c from W1/b1 (bit-identical to prior rounds' precise path).
__device__ float sdf_precise(float t, int lane, int q,
    float rox, float roy, float roz, float rdx, float rdy, float rdz,
    const float* __restrict__ W1, const float* __restrict__ b1,
    const bf16x8 (&w2f)[4][8],
    const f32x4* __restrict__ sB2q, const float4* __restrict__ sW3q, float b3v,
    const unsigned short* __restrict__ wlo)
{
  const bf16x8* wloF = (const bf16x8*)wlo;
  f32x4 acc[8];
  #pragma unroll
  for (int u = 0; u < 8; ++u) acc[u] = sB2q[u];

  #pragma unroll
  for (int s = 0; s < 4; ++s) {
    U8 HH, HL;
    #pragma unroll
    for (int p = 0; p < 4; ++p) {
      int k0 = 32 * s + 8 * q + 2 * p;
      int k1 = k0 + 1;
      float x0 = W1[k0], y0 = W1[HD + k0], z0 = W1[2 * HD + k0];
      float x1 = W1[k1], y1 = W1[HD + k1], z1 = W1[2 * HD + k1];
      float a0 = fmaf(x0, rox, fmaf(y0, roy, fmaf(z0, roz, b1[k0])));
      float a1 = fmaf(x1, rox, fmaf(y1, roy, fmaf(z1, roz, b1[k1])));
      float c0 = fmaf(x0, rdx, fmaf(y0, rdy, z0 * rdz));
      float c1 = fmaf(x1, rdx, fmaf(y1, rdy, z1 * rdz));
      float h0 = fmaxf(fmaf(c0, t, a0), 0.f);
      float h1 = fmaxf(fmaf(c1, t, a1), 0.f);
      unsigned short hb0 = f2bf(h0), hb1 = f2bf(h1);
      float r0 = h0 - __uint_as_float(((unsigned)hb0) << 16);
      float r1 = h1 - __uint_as_float(((unsigned)hb1) << 16);
      HH.us[2*p]     = hb0;      HH.us[2*p + 1] = hb1;
      HL.us[2*p]     = f2bf(r0); HL.us[2*p + 1] = f2bf(r1);
    }
    #pragma unroll
    for (int u = 0; u < 8; ++u) {
      bf16x8 wl = wloF[(s * 8 + u) * 64 + lane];
      acc[u] = __builtin_amdgcn_mfma_f32_16x16x32_bf16(w2f[s][u], HH.v, acc[u], 0, 0, 0);
      acc[u] = __builtin_amdgcn_mfma_f32_16x16x32_bf16(wl,        HH.v, acc[u], 0, 0, 0);
      acc[u] = __builtin_amdgcn_mfma_f32_16x16x32_bf16(w2f[s][u], HL.v, acc[u], 0, 0, 0);
    }
  }

  f32x2 z; z.x = 0.f; z.y = 0.f;
  f32x2 e0 = z, e1 = z, e2 = z, e3 = z;
  #pragma unroll
  for (int u = 0; u < 8; ++u) {
    float4 wv = sW3q[u];
    f32x2 wa; wa.x = wv.x; wa.y = wv.y;
    f32x2 wb; wb.x = wv.z; wb.y = wv.w;
    f32x4 y = acc[u];
    f32x2 lo; lo.x = fmaxf(y.x, 0.f); lo.y = fmaxf(y.y, 0.f);
    f32x2 hi; hi.x = fmaxf(y.z, 0.f); hi.y = fmaxf(y.w, 0.f);
    if (u & 1) { e2 = pk_fma(lo, wa, e2); e3 = pk_fma(hi, wb, e3); }
    else       { e0 = pk_fma(lo, wa, e0); e1 = pk_fma(hi, wb, e1); }
  }
  float d = (e0.x + e0.y) + (e1.x + e1.y) + ((e2.x + e2.y) + (e3.x + e3.y));
  d += __shfl_xor(d, 16);
  d += __shfl_xor(d, 32);
  return d + b3v;
}

// ---------- main: 1 wave = 16 rays, 2 waves/SIMD target ----------
__global__ __launch_bounds__(256, 2)
void render(const float* __restrict__ rays,
            const float* __restrict__ W1, const float* __restrict__ b1,
            const float* __restrict__ b2, const float* __restrict__ W3,
            const float* __restrict__ b3,
            const float* __restrict__ R1, const float* __restrict__ rb1,
            const float* __restrict__ R2, const float* __restrict__ rb2,
            const unsigned short* __restrict__ whi,
            const unsigned short* __restrict__ wlo,
            float* __restrict__ out, int nrays)
{
  // broadcast tables per quad: b2 C-init fragments + W3 pairs (1 KB)
  __shared__ float4 sB2[32];
  __shared__ float4 sW3[32];
  const int tid = threadIdx.x;
  if (tid < 32) {
    int u = tid & 7, qq = tid >> 3;
    int n0 = 16 * u + 4 * qq;
    sB2[tid] = *(const float4*)(b2 + n0);
    sW3[tid] = *(const float4*)(W3 + n0);
  }
  __syncthreads();

  const int lane = tid & 63;
  const int q    = lane >> 4;
  const int wv   = tid >> 6;
  const int ray  = blockIdx.x * 64 + wv * 16 + (lane & 15);

  const f32x4*  sB2q = (const f32x4*)(sB2 + q * 8);
  const float4* sW3q = sW3 + q * 8;

  // W2^T hi fragments resident: 128 VGPRs
  bf16x8 w2f[4][8];
  const bf16x8* whiF = (const bf16x8*)whi;
  #pragma unroll
  for (int s = 0; s < 4; ++s)
    #pragma unroll
    for (int u = 0; u < 8; ++u)
      w2f[s][u] = whiF[(s * 8 + u) * 64 + lane];

  const float b3v = b3[0];

  // a[k] fp32 (32 regs), c[k] packed bf16 (16 regs); ro/rd NOT kept resident
  f32x2 ap[16];
  unsigned cpk[16];
  {
    const float rox = rays[ray * 6 + 0], roy = rays[ray * 6 + 1], roz = rays[ray * 6 + 2];
    const float rdx = rays[ray * 6 + 3], rdy = rays[ray * 6 + 4], rdz = rays[ray * 6 + 5];
    #pragma unroll
    for (int s = 0; s < 4; ++s)
      #pragma unroll
      for (int p = 0; p < 4; ++p) {
        int k0 = 32 * s + 8 * q + 2 * p;
        int k1 = k0 + 1;
        float x0 = W1[k0], y0 = W1[HD + k0], z0 = W1[2 * HD + k0];
        float x1 = W1[k1], y1 = W1[HD + k1], z1 = W1[2 * HD + k1];
        f32x2 a;
        a.x = fmaf(x0, rox, fmaf(y0, roy, fmaf(z0, roz, b1[k0])));
        a.y = fmaf(x1, rox, fmaf(y1, roy, fmaf(z1, roz, b1[k1])));
        float c0 = fmaf(x0, rdx, fmaf(y0, rdy, z0 * rdz));
        float c1 = fmaf(x1, rdx, fmaf(y1, rdy, z1 * rdz));
        ap[4 * s + p] = a;
        cpk[4 * s + p] = pack2(c0, c1);
      }
  }

  // ---- sphere march (break when all 16 rays of the wave hit) ----
  float cd = T_NEAR;
  bool hit = false;
  #pragma unroll 1
  for (int it = 0; it < MARCH_N; ++it) {
    float d = sdf_fast(cd, w2f, ap, cpk, sB2q, sW3q, b3v);
    bool nh = (d < HIT_EPS) && (cd >= T_NEAR) && (cd <= T_FAR);
    hit = hit || nh;
    cd = hit ? cd : cd + d;
    if (__ballot(!hit) == 0ull) break;
  }

  // ---- tube scan: argmin of sdf over t = s*STEP, s = 0..32 ----
  float mn = sdf_fast(0.f, w2f, ap, cpk, sB2q, sW3q, b3v);
  int idx = 0;
  float ts = 0.f;
  #pragma unroll 1
  for (int s = 1; s <= TP_N; ++s) {
    ts += STEP;                       // exact (65*s/1024, s<=32)
    float d = sdf_fast(ts, w2f, ap, cpk, sB2q, sW3q, b3v);
    if (d < mn) { mn = d; idx = s; }
  }

  // ---- reload ray, reflectance (exact fp32), quad-split ----
  const float rox = rays[ray * 6 + 0], roy = rays[ray * 6 + 1], roz = rays[ray * 6 + 2];
  const float rdx = rays[ray * 6 + 3], rdy = rays[ray * 6 + 4], rdz = rays[ray * 6 + 5];
  const float ptx = fmaf(rdx, cd, rox);
  const float pty = fmaf(rdy, cd, roy);
  const float ptz = fmaf(rdz, cd, roz);
  float cr = 0.f, cg = 0.f, cb = 0.f;
  {
    int jb = q * 32;
    #pragma unroll 1
    for (int jj = 0; jj < 32; ++jj) {
      int j = jb + jj;
      float h = fmaf(R1[0 * HD + j], ptx,
                fmaf(R1[1 * HD + j], pty,
                fmaf(R1[2 * HD + j], ptz,
                fmaf(R1[3 * HD + j], rdx,
                fmaf(R1[4 * HD + j], rdy,
                fmaf(R1[5 * HD + j], rdz, rb1[j]))))));
      h = fmaxf(h, 0.f);
      cr = fmaf(h, R2[j * 3 + 0], cr);
      cg = fmaf(h, R2[j * 3 + 1], cg);
      cb = fmaf(h, R2[j * 3 + 2], cb);
    }
    cr += __shfl_xor(cr, 16); cr += __shfl_xor(cr, 32);
    cg += __shfl_xor(cg, 16); cg += __shfl_xor(cg, 32);
    cb += __shfl_xor(cb, 16); cb += __shfl_xor(cb, 32);
    cr += rb2[0]; cg += rb2[1]; cb += rb2[2];
  }

  // ---- final tput at best t, hi/lo split (fp32 a,c recompute) ----
  const float tb = STEP * (float)idx;
  const float tput = sdf_precise(tb, lane, q, rox, roy, roz, rdx, rdy, rdz,
                                 W1, b1, w2f, sB2q, sW3q, b3v, wlo);

  if (q == 0) {
    float4 o;
    o.x = hit ? cr : 0.f;
    o.y = hit ? cg : 0.f;
    o.z = hit ? cb : 0.f;
    o.w = -ALPHA_C * tput;
    ((float4*)out)[ray] = o;
  }
}

extern "C" void kernel_launch(void* const* d_in, const int* in_sizes, int n_in,
                              void* d_out, int out_size, void* d_ws, size_t ws_size,
                              hipStream_t stream) {
  const float* rays = (const float*)d_in[0];
  const float* W1  = (const float*)d_in[1];
  const float* b1  = (const float*)d_in[2];
  const float* W2  = (const float*)d_in[3];
  const float* b2  = (const float*)d_in[4];
  const float* W3  = (const float*)d_in[5];
  const float* b3  = (const float*)d_in[6];
  const float* R1  = (const float*)d_in[7];
  const float* rb1 = (const float*)d_in[8];
  const float* R2  = (const float*)d_in[9];
  const float* rb2 = (const float*)d_in[10];

  unsigned short* whi = (unsigned short*)d_ws;   // 32 KB
  unsigned short* wlo = whi + 128 * 128;         // 32 KB

  const int nrays = in_sizes[0] / 6;

  hipLaunchKernelGGL(pack_w2, dim3(64), dim3(256), 0, stream, W2, whi, wlo);
  hipLaunchKernelGGL(render, dim3(nrays / 64), dim3(256), 0, stream,
                     rays, W1, b1, b2, W3, b3, R1, rb1, R2, rb2,
                     whi, wlo, (float*)d_out, nrays);
}

// Round 7
// 3611.636 us; speedup vs baseline: 3.5457x; 3.5457x over previous
//
#include <hip/hip_runtime.h>

typedef __attribute__((ext_vector_type(8))) short bf16x8;
typedef __attribute__((ext_vector_type(4))) float f32x4;
typedef __attribute__((ext_vector_type(2))) float f32x2;

constexpr int   HD      = 128;
constexpr float T_NEAR  = 0.2f;
constexpr float T_FAR   = 2.0f;
constexpr float ALPHA_C = 100.0f;
constexpr int   MARCH_N = 32;
constexpr float HIT_EPS = 0.005f;
constexpr int   TP_N    = 32;
constexpr float STEP    = 0.0634765625f;  // (2.0 + 0.5*(2/32))/32, exact

// ---------- bf16 helpers ----------
__device__ __forceinline__ unsigned short f2bf(float x) {
  unsigned u = __float_as_uint(x);
  unsigned r = 0x7fffu + ((u >> 16) & 1u);
  return (unsigned short)((u + r) >> 16);
}
__device__ __forceinline__ unsigned pack2(float lo, float hi) {
  return (unsigned)f2bf(lo) | ((unsigned)f2bf(hi) << 16);
}
__device__ __forceinline__ float blo(unsigned u) { return __uint_as_float(u << 16); }
__device__ __forceinline__ float bhi(unsigned u) { return __uint_as_float(u & 0xffff0000u); }

union U8 { bf16x8 v; uint4 u4; unsigned short us[8]; };

__device__ __forceinline__ f32x2 pk_fma(f32x2 a, f32x2 b, f32x2 c) {
  f32x2 d;
  asm("v_pk_fma_f32 %0, %1, %2, %3" : "=v"(d) : "v"(a), "v"(b), "v"(c));
  return d;
}

// {h.x,h.y} -> packed bf16 pair (round-half-up) with relu in bf16-bit domain.
__device__ __forceinline__ unsigned pack_relu_pair(f32x2 h) {
  unsigned u0 = __float_as_uint(h.x) + 0x8000u;
  unsigned u1 = __float_as_uint(h.y) + 0x8000u;
  unsigned w, r;
  asm("v_perm_b32 %0, %1, %2, %3" : "=v"(w) : "v"(u1), "v"(u0), "s"(0x07060302u));
  asm("v_pk_max_i16 %0, %1, %2" : "=v"(r) : "v"(w), "v"(0u));
  return r;
}

// ---------- setup kernel: pack W2^T into per-lane MFMA A-fragments ----------
// A[m=16t+(lane&15)][k=32s+(lane>>4)*8+j] = W2[k*128+m]; hi + residual lo.
__global__ void pack_w2(const float* __restrict__ W2,
                        unsigned short* __restrict__ hi,
                        unsigned short* __restrict__ lo) {
  int idx = blockIdx.x * 256 + threadIdx.x;     // 0..16383
  int j = idx & 7, l = (idx >> 3) & 63, t = (idx >> 9) & 7, s = idx >> 12;
  int m = 16 * t + (l & 15);
  int k = 32 * s + (l >> 4) * 8 + j;
  float w = W2[k * HD + m];
  unsigned short h = f2bf(w);
  float hf = __uint_as_float(((unsigned)h) << 16);
  hi[idx] = h;
  lo[idx] = f2bf(w - hf);
}

// ---------- cross-wave pair combine through LDS (parity double-buffered) ----------
__device__ __forceinline__ float combine_pair(float part, float* __restrict__ sD,
                                              int slot, int wv, int lane) {
  float* base = sD + (slot & 1) * 64;
  if (lane < 16) base[wv * 16 + lane] = part;
  __syncthreads();
  return part + base[(wv ^ 1) * 16 + (lane & 15)];
}

// ---------- half-output SDF eval: wave-partial of sum(W3.relu(W2h+b2)) ----------
// Covers outputs m = 16*(hw*4+u)+... ; b2 folded as MFMA C-init. No b3 here.
__device__ __forceinline__ float sdf_half(float t,
    const bf16x8 (&w2h)[4][4], const f32x2 (&ap)[16], const unsigned (&cpk)[16],
    const f32x4 (&b2f)[4], const f32x2 (&w3p)[8])
{
  f32x2 t2; t2.x = t; t2.y = t;
  f32x4 acc[4];
  #pragma unroll
  for (int u = 0; u < 4; ++u) acc[u] = b2f[u];

  #pragma unroll
  for (int s = 0; s < 4; ++s) {
    U8 B;
    {
      unsigned uc0 = cpk[4*s+0], uc1 = cpk[4*s+1], uc2 = cpk[4*s+2], uc3 = cpk[4*s+3];
      f32x2 c0; c0.x = blo(uc0); c0.y = bhi(uc0);
      f32x2 c1; c1.x = blo(uc1); c1.y = bhi(uc1);
      f32x2 c2; c2.x = blo(uc2); c2.y = bhi(uc2);
      f32x2 c3; c3.x = blo(uc3); c3.y = bhi(uc3);
      B.u4.x = pack_relu_pair(pk_fma(c0, t2, ap[4*s+0]));
      B.u4.y = pack_relu_pair(pk_fma(c1, t2, ap[4*s+1]));
      B.u4.z = pack_relu_pair(pk_fma(c2, t2, ap[4*s+2]));
      B.u4.w = pack_relu_pair(pk_fma(c3, t2, ap[4*s+3]));
    }
    #pragma unroll
    for (int u = 0; u < 4; ++u)
      acc[u] = __builtin_amdgcn_mfma_f32_16x16x32_bf16(w2h[s][u], B.v, acc[u], 0, 0, 0);
  }

  f32x2 z; z.x = 0.f; z.y = 0.f;
  f32x2 e0 = z, e1 = z;
  #pragma unroll
  for (int u = 0; u < 4; ++u) {
    f32x4 y = acc[u];
    f32x2 lo; lo.x = fmaxf(y.x, 0.f); lo.y = fmaxf(y.y, 0.f);
    f32x2 hi; hi.x = fmaxf(y.z, 0.f); hi.y = fmaxf(y.w, 0.f);
    e0 = pk_fma(lo, w3p[2*u], e0);
    e1 = pk_fma(hi, w3p[2*u+1], e1);
  }
  float d = (e0.x + e0.y) + (e1.x + e1.y);
  d += __shfl_xor(d, 16);
  d += __shfl_xor(d, 32);
  return d;
}

// ---------- half-output hi/lo-split precise eval (x100 tput channel) ----------
__device__ float sdf_precise_half(float t, int lane, int q, int hw,
    float rox, float roy, float roz, float rdx, float rdy, float rdz,
    const float* __restrict__ W1, const float* __restrict__ b1,
    const bf16x8 (&w2h)[4][4], const f32x4 (&b2f)[4], const f32x2 (&w3p)[8],
    const unsigned short* __restrict__ wlo)
{
  const bf16x8* wloF = (const bf16x8*)wlo;
  f32x4 acc[4];
  #pragma unroll
  for (int u = 0; u < 4; ++u) acc[u] = b2f[u];

  #pragma unroll
  for (int s = 0; s < 4; ++s) {
    U8 HH, HL;
    #pragma unroll
    for (int p = 0; p < 4; ++p) {
      int k0 = 32 * s + 8 * q + 2 * p;
      int k1 = k0 + 1;
      float x0 = W1[k0], y0 = W1[HD + k0], z0 = W1[2 * HD + k0];
      float x1 = W1[k1], y1 = W1[HD + k1], z1 = W1[2 * HD + k1];
      float a0 = fmaf(x0, rox, fmaf(y0, roy, fmaf(z0, roz, b1[k0])));
      float a1 = fmaf(x1, rox, fmaf(y1, roy, fmaf(z1, roz, b1[k1])));
      float c0 = fmaf(x0, rdx, fmaf(y0, rdy, z0 * rdz));
      float c1 = fmaf(x1, rdx, fmaf(y1, rdy, z1 * rdz));
      float h0 = fmaxf(fmaf(c0, t, a0), 0.f);
      float h1 = fmaxf(fmaf(c1, t, a1), 0.f);
      unsigned short hb0 = f2bf(h0), hb1 = f2bf(h1);
      float r0 = h0 - __uint_as_float(((unsigned)hb0) << 16);
      float r1 = h1 - __uint_as_float(((unsigned)hb1) << 16);
      HH.us[2*p]     = hb0;      HH.us[2*p + 1] = hb1;
      HL.us[2*p]     = f2bf(r0); HL.us[2*p + 1] = f2bf(r1);
    }
    #pragma unroll
    for (int u = 0; u < 4; ++u) {
      bf16x8 wl = wloF[(s * 8 + hw * 4 + u) * 64 + lane];
      acc[u] = __builtin_amdgcn_mfma_f32_16x16x32_bf16(w2h[s][u], HH.v, acc[u], 0, 0, 0);
      acc[u] = __builtin_amdgcn_mfma_f32_16x16x32_bf16(wl,        HH.v, acc[u], 0, 0, 0);
      acc[u] = __builtin_amdgcn_mfma_f32_16x16x32_bf16(w2h[s][u], HL.v, acc[u], 0, 0, 0);
    }
  }

  f32x2 z; z.x = 0.f; z.y = 0.f;
  f32x2 e0 = z, e1 = z;
  #pragma unroll
  for (int u = 0; u < 4; ++u) {
    f32x4 y = acc[u];
    f32x2 lo; lo.x = fmaxf(y.x, 0.f); lo.y = fmaxf(y.y, 0.f);
    f32x2 hi; hi.x = fmaxf(y.z, 0.f); hi.y = fmaxf(y.w, 0.f);
    e0 = pk_fma(lo, w3p[2*u], e0);
    e1 = pk_fma(hi, w3p[2*u+1], e1);
  }
  float d = (e0.x + e0.y) + (e1.x + e1.y);
  d += __shfl_xor(d, 16);
  d += __shfl_xor(d, 32);
  return d;
}

// ---------- main: wave pair = 16 rays, each wave = half the outputs ----------
// WG = 256 thr = 4 waves = 2 pairs = 32 rays. 2 waves/SIMD (regs ~220 < 256).
__global__ __launch_bounds__(256, 2)
void render(const float* __restrict__ rays,
            const float* __restrict__ W1, const float* __restrict__ b1,
            const float* __restrict__ b2, const float* __restrict__ W3,
            const float* __restrict__ b3,
            const float* __restrict__ R1, const float* __restrict__ rb1,
            const float* __restrict__ R2, const float* __restrict__ rb2,
            const unsigned short* __restrict__ whi,
            const unsigned short* __restrict__ wlo,
            float* __restrict__ out, int nrays)
{
  __shared__ float sD[2 * 64];   // parity-double-buffered pair-combine slots

  const int tid  = threadIdx.x;
  const int lane = tid & 63;
  const int q    = lane >> 4;
  const int wv   = tid >> 6;       // 0..3
  const int hw   = wv & 1;         // output half
  const int pr   = wv >> 1;        // pair id
  const int ray  = blockIdx.x * 32 + pr * 16 + (lane & 15);

  // W2^T half fragments resident: 64 VGPRs (t_global = hw*4 + u)
  bf16x8 w2h[4][4];
  const bf16x8* whiF = (const bf16x8*)whi;
  #pragma unroll
  for (int s = 0; s < 4; ++s)
    #pragma unroll
    for (int u = 0; u < 4; ++u)
      w2h[s][u] = whiF[(s * 8 + hw * 4 + u) * 64 + lane];

  const float b3v = b3[0];

  // b2 C-init fragments + W3 pairs for this wave's outputs (n0=16*(hw*4+u)+4q)
  f32x4 b2f[4];
  f32x2 w3p[8];
  #pragma unroll
  for (int u = 0; u < 4; ++u) {
    int n0 = 16 * (hw * 4 + u) + 4 * q;
    float4 bb = *(const float4*)(b2 + n0);
    f32x4 bv; bv.x = bb.x; bv.y = bb.y; bv.z = bb.z; bv.w = bb.w;
    b2f[u] = bv;
    float4 wq = *(const float4*)(W3 + n0);
    f32x2 wa; wa.x = wq.x; wa.y = wq.y;
    f32x2 wb; wb.x = wq.z; wb.y = wq.w;
    w3p[2 * u] = wa; w3p[2 * u + 1] = wb;
  }

  // a[k] fp32 (32 regs), c[k] packed bf16 (16 regs); ro/rd not kept resident
  f32x2 ap[16];
  unsigned cpk[16];
  {
    const float rox = rays[ray * 6 + 0], roy = rays[ray * 6 + 1], roz = rays[ray * 6 + 2];
    const float rdx = rays[ray * 6 + 3], rdy = rays[ray * 6 + 4], rdz = rays[ray * 6 + 5];
    #pragma unroll
    for (int s = 0; s < 4; ++s)
      #pragma unroll
      for (int p = 0; p < 4; ++p) {
        int k0 = 32 * s + 8 * q + 2 * p;
        int k1 = k0 + 1;
        float x0 = W1[k0], y0 = W1[HD + k0], z0 = W1[2 * HD + k0];
        float x1 = W1[k1], y1 = W1[HD + k1], z1 = W1[2 * HD + k1];
        f32x2 a;
        a.x = fmaf(x0, rox, fmaf(y0, roy, fmaf(z0, roz, b1[k0])));
        a.y = fmaf(x1, rox, fmaf(y1, roy, fmaf(z1, roz, b1[k1])));
        float c0 = fmaf(x0, rdx, fmaf(y0, rdy, z0 * rdz));
        float c1 = fmaf(x1, rdx, fmaf(y1, rdy, z1 * rdz));
        ap[4 * s + p] = a;
        cpk[4 * s + p] = pack2(c0, c1);
      }
  }
  __syncthreads();   // sD ready-to-use fence (also spaces the staggered setup)

  int slot = 0;

  // ---- sphere march: 32 uniform iters (no break -> barrier-safe) ----
  float cd = T_NEAR;
  bool hit = false;
  #pragma unroll 1
  for (int it = 0; it < MARCH_N; ++it) {
    float p = sdf_half(cd, w2h, ap, cpk, b2f, w3p);
    float d = combine_pair(p, sD, slot++, wv, lane) + b3v;
    bool nh = (d < HIT_EPS) && (cd >= T_NEAR) && (cd <= T_FAR);
    hit = hit || nh;
    cd = hit ? cd : cd + d;
  }

  // ---- tube scan: argmin over t = s*STEP, s = 0..32 ----
  float mn = combine_pair(sdf_half(0.f, w2h, ap, cpk, b2f, w3p),
                          sD, slot++, wv, lane) + b3v;
  int idx = 0;
  float ts = 0.f;
  #pragma unroll 1
  for (int s = 1; s <= TP_N; ++s) {
    ts += STEP;                       // exact (65*s/1024, s<=32)
    float p = sdf_half(ts, w2h, ap, cpk, b2f, w3p);
    float d = combine_pair(p, sD, slot++, wv, lane) + b3v;
    if (d < mn) { mn = d; idx = s; }
  }

  // ---- reload ray; reflectance (exact fp32): 64 j's per wave, 16 per quad ----
  const float rox = rays[ray * 6 + 0], roy = rays[ray * 6 + 1], roz = rays[ray * 6 + 2];
  const float rdx = rays[ray * 6 + 3], rdy = rays[ray * 6 + 4], rdz = rays[ray * 6 + 5];
  const float ptx = fmaf(rdx, cd, rox);
  const float pty = fmaf(rdy, cd, roy);
  const float ptz = fmaf(rdz, cd, roz);
  float cr = 0.f, cg = 0.f, cb = 0.f;
  {
    int jb = hw * 64 + q * 16;
    #pragma unroll 1
    for (int jj = 0; jj < 16; ++jj) {
      int j = jb + jj;
      float h = fmaf(R1[0 * HD + j], ptx,
                fmaf(R1[1 * HD + j], pty,
                fmaf(R1[2 * HD + j], ptz,
                fmaf(R1[3 * HD + j], rdx,
                fmaf(R1[4 * HD + j], rdy,
                fmaf(R1[5 * HD + j], rdz, rb1[j]))))));
      h = fmaxf(h, 0.f);
      cr = fmaf(h, R2[j * 3 + 0], cr);
      cg = fmaf(h, R2[j * 3 + 1], cg);
      cb = fmaf(h, R2[j * 3 + 2], cb);
    }
    cr += __shfl_xor(cr, 16); cr += __shfl_xor(cr, 32);
    cg += __shfl_xor(cg, 16); cg += __shfl_xor(cg, 32);
    cb += __shfl_xor(cb, 16); cb += __shfl_xor(cb, 32);
    cr = combine_pair(cr, sD, slot++, wv, lane) + rb2[0];
    cg = combine_pair(cg, sD, slot++, wv, lane) + rb2[1];
    cb = combine_pair(cb, sD, slot++, wv, lane) + rb2[2];
  }

  // ---- final tput at best t, hi/lo split, pair-combined ----
  const float tb = STEP * (float)idx;
  float tp = sdf_precise_half(tb, lane, q, hw, rox, roy, roz, rdx, rdy, rdz,
                              W1, b1, w2h, b2f, w3p, wlo);
  const float tput = combine_pair(tp, sD, slot++, wv, lane) + b3v;

  if (hw == 0 && q == 0) {
    float4 o;
    o.x = hit ? cr : 0.f;
    o.y = hit ? cg : 0.f;
    o.z = hit ? cb : 0.f;
    o.w = -ALPHA_C * tput;
    ((float4*)out)[ray] = o;
  }
}

extern "C" void kernel_launch(void* const* d_in, const int* in_sizes, int n_in,
                              void* d_out, int out_size, void* d_ws, size_t ws_size,
                              hipStream_t stream) {
  const float* rays = (const float*)d_in[0];
  const float* W1  = (const float*)d_in[1];
  const float* b1  = (const float*)d_in[2];
  const float* W2  = (const float*)d_in[3];
  const float* b2  = (const float*)d_in[4];
  const float* W3  = (const float*)d_in[5];
  const float* b3  = (const float*)d_in[6];
  const float* R1  = (const float*)d_in[7];
  const float* rb1 = (const float*)d_in[8];
  const float* R2  = (const float*)d_in[9];
  const float* rb2 = (const float*)d_in[10];

  unsigned short* whi = (unsigned short*)d_ws;   // 32 KB
  unsigned short* wlo = whi + 128 * 128;         // 32 KB

  const int nrays = in_sizes[0] / 6;

  hipLaunchKernelGGL(pack_w2, dim3(64), dim3(256), 0, stream, W2, whi, wlo);
  hipLaunchKernelGGL(render, dim3(nrays / 32), dim3(256), 0, stream,
                     rays, W1, b1, b2, W3, b3, R1, rb1, R2, rb2,
                     whi, wlo, (float*)d_out, nrays);
}